// Round 1
// baseline (247.715 us; speedup 1.0000x reference)
//
#include <hip/hip_runtime.h>
#include <math.h>

#define BQ   15      // queries
#define NN   5       // classes
#define SS   5       // shots
#define CH   64      // channels
#define HW   21      // spatial side
#define P    441     // 21*21
#define WIN  11
#define OH   11      // 21 - 10
#define OP   121     // 11*11
#define TP   231     // 11*21 (after row blur)

__device__ __forceinline__ void make_win(float* w) {
    float s = 0.f;
#pragma unroll
    for (int i = 0; i < WIN; ++i) {
        float c = (float)i - 5.0f;
        w[i] = expf(-(c * c) / 4.5f);   // 2*sigma^2 = 4.5
        s += w[i];
    }
    float inv = 1.0f / s;
#pragma unroll
    for (int i = 0; i < WIN; ++i) w[i] *= inv;
}

// in: (nimg, P, CH) row-major  ->  out: (nimg, CH, P), L2-normalized over CH per position
__global__ void normalize_transpose(const float* __restrict__ in, float* __restrict__ out) {
    int img = blockIdx.x;
    const float* src = in + (size_t)img * P * CH;
    float* dst = out + (size_t)img * CH * P;
    __shared__ float invn[P];
    for (int p = threadIdx.x; p < P; p += blockDim.x) {
        const float* v = src + p * CH;
        float s = 0.f;
#pragma unroll 8
        for (int c = 0; c < CH; ++c) { float x = v[c]; s += x * x; }
        invn[p] = rsqrtf(s);
    }
    __syncthreads();
    for (int idx = threadIdx.x; idx < CH * P; idx += blockDim.x) {
        int c = idx / P, p = idx - c * P;
        dst[idx] = src[p * CH + c] * invn[p];
    }
}

// one block per (img*CH + c): separable gaussian blur of x and x^2 -> mu (OP), sq (OP)
__global__ void blur_stats(const float* __restrict__ tn, float* __restrict__ mu,
                           float* __restrict__ sq) {
    int ic = blockIdx.x;
    const float* src = tn + (size_t)ic * P;
    __shared__ float ch[P];
    __shared__ float t1[TP], t2[TP];
    float w[WIN]; make_win(w);
    for (int p = threadIdx.x; p < P; p += blockDim.x) ch[p] = src[p];
    __syncthreads();
    // blur along H (row index i)
    for (int t = threadIdx.x; t < TP; t += blockDim.x) {
        int i = t / HW, j = t - i * HW;
        float a1 = 0.f, a2 = 0.f;
#pragma unroll
        for (int a = 0; a < WIN; ++a) {
            float x = ch[(i + a) * HW + j];
            a1 += w[a] * x;
            a2 += w[a] * x * x;
        }
        t1[t] = a1; t2[t] = a2;
    }
    __syncthreads();
    // blur along W
    for (int t = threadIdx.x; t < OP; t += blockDim.x) {
        int i = t / OH, j = t - i * OH;
        float a1 = 0.f, a2 = 0.f;
#pragma unroll
        for (int a = 0; a < WIN; ++a) {
            a1 += w[a] * t1[i * HW + j + a];
            a2 += w[a] * t2[i * HW + j + a];
        }
        mu[(size_t)ic * OP + t] = a1;
        sq[(size_t)ic * OP + t] = a2;
    }
}

// grid (375 pairs, 64 channels), block 128
__global__ void ssim_pairs(const float* __restrict__ qn, const float* __restrict__ sn,
                           const float* __restrict__ mu1, const float* __restrict__ s1,
                           const float* __restrict__ mu2, const float* __restrict__ s2,
                           float* __restrict__ out) {
    int pair = blockIdx.x;     // 0..374  = b*25 + n*5 + si
    int c    = blockIdx.y;     // 0..63
    int b    = pair / (NN * SS);
    int rem  = pair - b * (NN * SS);
    int n    = rem / SS;
    int si   = rem - n * SS;

    const float* X = qn + ((size_t)b * CH + c) * P;
    const float* Y = sn + ((size_t)(n * SS + si) * CH + c) * P;

    __shared__ float xy[P];
    __shared__ float t1[TP];
    float w[WIN]; make_win(w);

    for (int p = threadIdx.x; p < P; p += blockDim.x) xy[p] = X[p] * Y[p];
    __syncthreads();
    for (int t = threadIdx.x; t < TP; t += blockDim.x) {
        int i = t / HW, j = t - (t / HW) * HW;
        float a1 = 0.f;
#pragma unroll
        for (int a = 0; a < WIN; ++a) a1 += w[a] * xy[(i + a) * HW + j];
        t1[t] = a1;
    }
    __syncthreads();

    const float C1 = 1e-4f, C2 = 9e-4f;
    size_t o1 = ((size_t)b * CH + c) * OP;
    size_t o2 = ((size_t)(n * SS + si) * CH + c) * OP;
    float part = 0.f;
    for (int t = threadIdx.x; t < OP; t += blockDim.x) {
        int i = t / OH, j = t - (t / OH) * OH;
        float sxy = 0.f;
#pragma unroll
        for (int a = 0; a < WIN; ++a) sxy += w[a] * t1[i * HW + j + a];
        float m1 = mu1[o1 + t], m2 = mu2[o2 + t];
        float v1 = s1[o1 + t] - m1 * m1;
        float v2 = s2[o2 + t] - m2 * m2;
        float cov = sxy - m1 * m2;
        float num = (2.f * m1 * m2 + C1) * (2.f * cov + C2);
        float den = (m1 * m1 + m2 * m2 + C1) * (v1 + v2 + C2);
        part += num / den;
    }

    // block reduce: 2 waves of 64
#pragma unroll
    for (int off = 32; off > 0; off >>= 1) part += __shfl_down(part, off, 64);
    __shared__ float wsum[2];
    if ((threadIdx.x & 63) == 0) wsum[threadIdx.x >> 6] = part;
    __syncthreads();
    if (threadIdx.x == 0)
        atomicAdd(&out[b * NN + n], (wsum[0] + wsum[1]) * (1.0f / (CH * OP)));
}

extern "C" void kernel_launch(void* const* d_in, const int* in_sizes, int n_in,
                              void* d_out, int out_size, void* d_ws, size_t ws_size,
                              hipStream_t stream) {
    const float* x1 = (const float*)d_in[0];   // (15, 441, 64)
    const float* x2 = (const float*)d_in[1];   // (5, 5, 441, 64)
    float* out = (float*)d_out;                // (15, 5)
    float* ws  = (float*)d_ws;

    float* qn  = ws;                                   // BQ*CH*P
    float* sn  = qn  + (size_t)BQ * CH * P;            // 25*CH*P
    float* mu1 = sn  + (size_t)NN * SS * CH * P;       // BQ*CH*OP
    float* s1  = mu1 + (size_t)BQ * CH * OP;
    float* mu2 = s1  + (size_t)BQ * CH * OP;           // 25*CH*OP
    float* s2  = mu2 + (size_t)NN * SS * CH * OP;

    hipMemsetAsync(d_out, 0, (size_t)out_size * sizeof(float), stream);

    normalize_transpose<<<BQ, 256, 0, stream>>>(x1, qn);
    normalize_transpose<<<NN * SS, 256, 0, stream>>>(x2, sn);
    blur_stats<<<BQ * CH, 128, 0, stream>>>(qn, mu1, s1);
    blur_stats<<<NN * SS * CH, 128, 0, stream>>>(sn, mu2, s2);

    dim3 grid(BQ * NN * SS, CH);
    ssim_pairs<<<grid, 128, 0, stream>>>(qn, sn, mu1, s1, mu2, s2, out);
}

// Round 2
// 100.773 us; speedup vs baseline: 2.4582x; 2.4582x over previous
//
#include <hip/hip_runtime.h>

#define BQ   15      // queries
#define NIMG 40      // 15 queries + 25 supports, concatenated
#define CH   64
#define HW   21
#define P    441     // 21*21
#define WIN  11
#define OH   11
#define OP   121     // 11*11
#define TP   231     // 11*21

// Gaussian window (sigma=1.5, 11 taps), precomputed — no expf at runtime.
__device__ __forceinline__ float Wf(int a) {
    constexpr float w[WIN] = {
        0.0010283804f, 0.0075988025f, 0.0360007770f, 0.1093606993f,
        0.2130055427f, 0.2660117290f, 0.2130055427f, 0.1093606993f,
        0.0360007770f, 0.0075988025f, 0.0010283804f};
    return w[a];
}

// ---------------------------------------------------------------------------
// prep: normalize over channels + transpose (img, P, CH) -> tn (img, CH, P)
// grid (40, 7), block 256; each block handles 63 spatial positions.
// ---------------------------------------------------------------------------
__global__ void __launch_bounds__(256) prep_kernel(const float* __restrict__ x1,
                                                   const float* __restrict__ x2,
                                                   float* __restrict__ tn) {
    int img = blockIdx.x;           // 0..39
    int p0  = blockIdx.y * 63;      // 7 chunks of 63 = 441
    const float* src = (img < BQ) ? (x1 + (size_t)img * P * CH)
                                  : (x2 + (size_t)(img - BQ) * P * CH);
    float* dst = tn + (size_t)img * CH * P;

    __shared__ float tile[63 * 65];
    __shared__ float invn[63];

    for (int i = threadIdx.x; i < 63 * CH; i += 256) {
        int p = i >> 6, c = i & 63;
        tile[p * 65 + c] = src[(size_t)p0 * CH + i];   // fully coalesced
    }
    __syncthreads();
    if (threadIdx.x < 63) {
        int p = threadIdx.x;
        float s = 0.f;
#pragma unroll
        for (int c = 0; c < CH; ++c) { float v = tile[p * 65 + c]; s += v * v; }
        invn[p] = rsqrtf(s);
    }
    __syncthreads();
    for (int i = threadIdx.x; i < 63 * CH; i += 256) {
        int c = i / 63, p = i - c * 63;
        dst[(size_t)c * P + p0 + p] = tile[p * 65 + c] * invn[p];
    }
}

// ---------------------------------------------------------------------------
// stats: per channel-image, separable blur of x and x^2 -> mu, sq (121 each)
// grid 320, block 256; 8 channels per block. Row blur uses addr = t + 21a.
// LDS layout per channel (stride 920): [0,441) data, [448,679) t1, [684,915) t2
// ---------------------------------------------------------------------------
__global__ void __launch_bounds__(256) stats_kernel(const float* __restrict__ tn,
                                                    float* __restrict__ mu,
                                                    float* __restrict__ sq) {
    __shared__ float lds[8 * 920];
    int cb = blockIdx.x * 8;        // global channel-image base, < 2560

    for (int i = threadIdx.x; i < 8 * P; i += 256) {
        int k = i / P, t = i - k * P;
        lds[k * 920 + t] = tn[(size_t)(cb + k) * P + t];
    }
    __syncthreads();
    for (int i = threadIdx.x; i < 8 * TP; i += 256) {
        int k = i / TP, t = i - k * TP;
        const float* x = lds + k * 920;
        float a1 = 0.f, a2 = 0.f;
#pragma unroll
        for (int a = 0; a < WIN; ++a) {
            float v = x[t + 21 * a];              // sequential addresses
            a1 = fmaf(Wf(a), v, a1);
            a2 = fmaf(Wf(a) * v, v, a2);
        }
        lds[k * 920 + 448 + t] = a1;
        lds[k * 920 + 684 + t] = a2;
    }
    __syncthreads();
    for (int i = threadIdx.x; i < 8 * OP; i += 256) {
        int k = i / OP, t = i - k * OP;
        int r = t / OH, cc = t - r * OH;
        int b0 = r * HW + cc;
        const float* t1 = lds + k * 920 + 448;
        const float* t2 = lds + k * 920 + 684;
        float a1 = 0.f, a2 = 0.f;
#pragma unroll
        for (int a = 0; a < WIN; ++a) {
            a1 = fmaf(Wf(a), t1[b0 + a], a1);
            a2 = fmaf(Wf(a), t2[b0 + a], a2);
        }
        size_t o = (size_t)(cb + k) * OP + t;
        mu[o] = a1;
        sq[o] = a2;
    }
}

// ---------------------------------------------------------------------------
// pairs: grid (375, 4), block 256; 16 channels per block, 3 barriers total.
// LDS per channel (stride 684): [0,441) xy, [448,679) row-blurred t1.
// ---------------------------------------------------------------------------
__global__ void __launch_bounds__(256) pairs_kernel(const float* __restrict__ tn,
                                                    const float* __restrict__ mu,
                                                    const float* __restrict__ sq,
                                                    float* __restrict__ out) {
    __shared__ float lds[16 * 684];
    __shared__ float ws4[4];

    int pair = blockIdx.x;          // 0..374
    int b    = pair / 25;
    int rem  = pair - b * 25;       // support image index (n*5 + si)
    int cb   = blockIdx.y * 16;     // channel base

    const float* X = tn + ((size_t)b * CH + cb) * P;
    const float* Y = tn + ((size_t)(BQ + rem) * CH + cb) * P;

    for (int i = threadIdx.x; i < 16 * P; i += 256) {
        int k = i / P, t = i - k * P;
        lds[k * 684 + t] = X[(size_t)k * P + t] * Y[(size_t)k * P + t];
    }
    __syncthreads();
    for (int i = threadIdx.x; i < 16 * TP; i += 256) {
        int k = i / TP, t = i - k * TP;
        const float* x = lds + k * 684;
        float a1 = 0.f;
#pragma unroll
        for (int a = 0; a < WIN; ++a) a1 = fmaf(Wf(a), x[t + 21 * a], a1);
        lds[k * 684 + 448 + t] = a1;
    }
    __syncthreads();

    const float C1 = 1e-4f, C2 = 9e-4f;
    size_t oq = ((size_t)b * CH + cb) * OP;
    size_t os = ((size_t)(BQ + rem) * CH + cb) * OP;
    float part = 0.f;
    for (int i = threadIdx.x; i < 16 * OP; i += 256) {
        int k = i / OP, t = i - k * OP;
        int r = t / OH, cc = t - r * OH;
        const float* t1 = lds + k * 684 + 448;
        float sxy = 0.f;
#pragma unroll
        for (int a = 0; a < WIN; ++a) sxy = fmaf(Wf(a), t1[r * HW + cc + a], sxy);
        float m1 = mu[oq + k * OP + t], m2 = mu[os + k * OP + t];
        float v1 = sq[oq + k * OP + t] - m1 * m1;
        float v2 = sq[os + k * OP + t] - m2 * m2;
        float cov = sxy - m1 * m2;
        part += ((2.f * m1 * m2 + C1) * (2.f * cov + C2)) /
                ((m1 * m1 + m2 * m2 + C1) * (v1 + v2 + C2));
    }

    // block reduce: 4 waves of 64
#pragma unroll
    for (int off = 32; off > 0; off >>= 1) part += __shfl_down(part, off, 64);
    if ((threadIdx.x & 63) == 0) ws4[threadIdx.x >> 6] = part;
    __syncthreads();
    if (threadIdx.x == 0) {
        int n = rem / 5;
        atomicAdd(&out[b * 5 + n],
                  (ws4[0] + ws4[1] + ws4[2] + ws4[3]) * (1.0f / (CH * OP)));
    }
}

extern "C" void kernel_launch(void* const* d_in, const int* in_sizes, int n_in,
                              void* d_out, int out_size, void* d_ws, size_t ws_size,
                              hipStream_t stream) {
    const float* x1 = (const float*)d_in[0];   // (15, 441, 64)
    const float* x2 = (const float*)d_in[1];   // (5, 5, 441, 64)
    float* out = (float*)d_out;                // (15, 5)
    float* ws  = (float*)d_ws;

    float* tn = ws;                                  // 40*64*441
    float* mu = tn + (size_t)NIMG * CH * P;          // 2560*121
    float* sq = mu + (size_t)NIMG * CH * OP;         // 2560*121

    hipMemsetAsync(d_out, 0, (size_t)out_size * sizeof(float), stream);

    prep_kernel<<<dim3(NIMG, 7), 256, 0, stream>>>(x1, x2, tn);
    stats_kernel<<<NIMG * CH / 8, 256, 0, stream>>>(tn, mu, sq);
    pairs_kernel<<<dim3(375, 4), 256, 0, stream>>>(tn, mu, sq, out);
}